// Round 1
// baseline (524.324 us; speedup 1.0000x reference)
//
#include <hip/hip_runtime.h>

// Problem constants (B=64, T=512, I=256, H=512)
#define BATCH 64
#define TSTEPS 512
#define IDIM 256
#define HDIM 512
#define MROWS (BATCH * TSTEPS)   // 32768

// ---------------------------------------------------------------------------
// K0: extract center taps: W1T[i][h] = conv1_w[h][i][1]; W2T[h][j] = conv2_w[j][h][1]
// ---------------------------------------------------------------------------
__global__ void extract_weights(const float* __restrict__ c1w,
                                const float* __restrict__ c2w,
                                float* __restrict__ W1T,
                                float* __restrict__ W2T) {
    int tid = blockIdx.x * 256 + threadIdx.x;
    if (tid < IDIM * HDIM) {
        int i = tid >> 9;          // / 512
        int h = tid & 511;
        W1T[tid] = c1w[(h * IDIM + i) * 3 + 1];
    }
    if (tid < HDIM * HDIM) {
        int h = tid >> 9;
        int j = tid & 511;
        W2T[tid] = c2w[(j * HDIM + h) * 3 + 1];
    }
}

// ---------------------------------------------------------------------------
// Generic fp32 GEMM: C[m][n] = sum_k A[m][k] * BT[k][n]  (+ bias[n] if addBias)
// Strictly sequential k-order per accumulator (numerics: closest to naive ref).
// BM=64, BN=64, BK=16, 256 threads, 4x4 per-thread tile.
// ---------------------------------------------------------------------------
#define BM 64
#define BN 64
#define BK 16

__global__ __launch_bounds__(256) void gemm_f32(const float* __restrict__ A,
                                                const float* __restrict__ BT,
                                                const float* __restrict__ bias,
                                                float* __restrict__ C,
                                                int K, int addBias) {
    __shared__ float As[BK][BM + 1];   // +1 pad: avoid 16-way bank conflict on store
    __shared__ float Bs[BK][BN];

    const int N = HDIM;
    int row0 = blockIdx.x * BM;
    int col0 = blockIdx.y * BN;
    int tid = threadIdx.x;
    int tn = tid & 15;        // 0..15
    int tm = tid >> 4;        // 0..15

    float acc[4][4];
#pragma unroll
    for (int i = 0; i < 4; i++)
#pragma unroll
        for (int j = 0; j < 4; j++) acc[i][j] = 0.0f;

    for (int k0 = 0; k0 < K; k0 += BK) {
        // stage A tile (64 rows x 16 k), 4 elems/thread
        {
            int kk = tid & (BK - 1);   // 0..15
            int mm = tid >> 4;         // 0..15
#pragma unroll
            for (int i = 0; i < 4; i++) {
                As[kk][mm + 16 * i] =
                    A[(size_t)(row0 + mm + 16 * i) * K + (k0 + kk)];
            }
        }
        // stage B tile (16 k x 64 n), 4 elems/thread, coalesced 64-wide
        {
            int nn = tid & (BN - 1);   // 0..63
            int kk = tid >> 6;         // 0..3
#pragma unroll
            for (int i = 0; i < 4; i++) {
                Bs[kk + 4 * i][nn] =
                    BT[(size_t)(k0 + kk + 4 * i) * N + (col0 + nn)];
            }
        }
        __syncthreads();
#pragma unroll
        for (int k = 0; k < BK; k++) {
            float a[4], b[4];
#pragma unroll
            for (int i = 0; i < 4; i++) a[i] = As[k][tm * 4 + i];
#pragma unroll
            for (int j = 0; j < 4; j++) b[j] = Bs[k][tn * 4 + j];
#pragma unroll
            for (int i = 0; i < 4; i++)
#pragma unroll
                for (int j = 0; j < 4; j++)
                    acc[i][j] = fmaf(a[i], b[j], acc[i][j]);
        }
        __syncthreads();
    }

#pragma unroll
    for (int i = 0; i < 4; i++)
#pragma unroll
        for (int j = 0; j < 4; j++) {
            float v = acc[i][j];
            if (addBias) v += bias[col0 + tn * 4 + j];
            C[(size_t)(row0 + tm * 4 + i) * N + (col0 + tn * 4 + j)] = v;
        }
}

// ---------------------------------------------------------------------------
// K2: per-(b,h) LIF scan over t: m1 += z1[t]; spike at m1/th-1 >= 0; reset if > 0.
// Writes s1 in {0.0, 1.0}. 8-deep load batching to amortize memory latency
// (only 512 waves exist -> 2 waves/CU; MLP is the only latency hiding).
// ---------------------------------------------------------------------------
__global__ void lif_scan1(const float* __restrict__ z1,
                          float* __restrict__ s1,
                          const float* __restrict__ th_p) {
    int gtid = blockIdx.x * blockDim.x + threadIdx.x;   // 0..32767
    int b = gtid >> 9;
    int h = gtid & 511;
    float th = *th_p;
    const float* zp = z1 + (size_t)b * TSTEPS * HDIM + h;
    float* sp = s1 + (size_t)b * TSTEPS * HDIM + h;
    float m = 0.0f;
    for (int t0 = 0; t0 < TSTEPS; t0 += 8) {
        float zz[8];
#pragma unroll
        for (int i = 0; i < 8; i++) zz[i] = zp[(size_t)(t0 + i) * HDIM];
        float ss[8];
#pragma unroll
        for (int i = 0; i < 8; i++) {
            m += zz[i];
            float thr = m / th - 1.0f;
            ss[i] = (thr >= 0.0f) ? 1.0f : 0.0f;
            if (thr > 0.0f) m -= th;   // exact: m - th*1.0
        }
#pragma unroll
        for (int i = 0; i < 8; i++) sp[(size_t)(t0 + i) * HDIM] = ss[i];
    }
}

// ---------------------------------------------------------------------------
// K4: per-(b,j) scan: m2 = (m2 + raw[t]) + bias  (association matches ref:
// ((leak*m2) + dot) + conv2_b), then spike/reset; writes s2 to out.
// ---------------------------------------------------------------------------
__global__ void lif_scan2(const float* __restrict__ raw,
                          const float* __restrict__ b2,
                          const float* __restrict__ th_p,
                          float* __restrict__ out) {
    int gtid = blockIdx.x * blockDim.x + threadIdx.x;   // 0..32767
    int b = gtid >> 9;
    int j = gtid & 511;
    float th = *th_p;
    float bias = b2[j];
    const float* rp = raw + (size_t)b * TSTEPS * HDIM + j;
    float* op = out + (size_t)b * TSTEPS * HDIM + j;
    float m = 0.0f;
    for (int t0 = 0; t0 < TSTEPS; t0 += 8) {
        float rr[8];
#pragma unroll
        for (int i = 0; i < 8; i++) rr[i] = rp[(size_t)(t0 + i) * HDIM];
        float ss[8];
#pragma unroll
        for (int i = 0; i < 8; i++) {
            m = (m + rr[i]) + bias;
            float thr = m / th - 1.0f;
            ss[i] = (thr >= 0.0f) ? 1.0f : 0.0f;
            if (thr > 0.0f) m -= th;
        }
#pragma unroll
        for (int i = 0; i < 8; i++) op[(size_t)(t0 + i) * HDIM] = ss[i];
    }
}

// ---------------------------------------------------------------------------
extern "C" void kernel_launch(void* const* d_in, const int* in_sizes, int n_in,
                              void* d_out, int out_size, void* d_ws, size_t ws_size,
                              hipStream_t stream) {
    const float* x    = (const float*)d_in[0];   // (64, 512, 256)
    const float* c1w  = (const float*)d_in[1];   // (512, 256, 3)
    const float* c1b  = (const float*)d_in[2];   // (512,)
    const float* c2w  = (const float*)d_in[3];   // (512, 512, 3)
    const float* c2b  = (const float*)d_in[4];   // (512,)
    const float* th1  = (const float*)d_in[5];   // scalar
    const float* th2  = (const float*)d_in[6];   // scalar
    float* out = (float*)d_out;                  // (64, 512, 512)

    // Workspace layout (floats):
    //   W1T: IDIM*HDIM = 131072        (W1T[i][h])
    //   W2T: HDIM*HDIM = 262144        (W2T[h][j])
    //   bufA: 16777216                 (z1, later overwritten by m2raw)
    //   bufS: 16777216                 (s1)
    // total ~135.8 MB
    float* W1T  = (float*)d_ws;
    float* W2T  = W1T + IDIM * HDIM;
    float* bufA = W2T + HDIM * HDIM;
    float* bufS = bufA + (size_t)MROWS * HDIM;

    // K0: weight extraction (center taps, transposed layouts)
    extract_weights<<<(HDIM * HDIM + 255) / 256, 256, 0, stream>>>(c1w, c2w, W1T, W2T);

    // K1: z1 = x @ W1T + b1   (M=32768, K=256, N=512) -> bufA
    {
        dim3 grid(MROWS / BM, HDIM / BN);
        gemm_f32<<<grid, 256, 0, stream>>>(x, W1T, c1b, bufA, IDIM, 1);
    }

    // K2: s1 scan -> bufS
    lif_scan1<<<MROWS / 256, 256, 0, stream>>>(bufA, bufS, th1);

    // K3: m2raw = s1 @ W2T   (M=32768, K=512, N=512) -> bufA (z1 dead)
    {
        dim3 grid(MROWS / BM, HDIM / BN);
        gemm_f32<<<grid, 256, 0, stream>>>(bufS, W2T, (const float*)nullptr, bufA, HDIM, 0);
    }

    // K4: s2 scan -> out
    lif_scan2<<<MROWS / 256, 256, 0, stream>>>(bufA, c2b, th2, out);
}

// Round 4
// 437.629 us; speedup vs baseline: 1.1981x; 1.1981x over previous
//
#include <hip/hip_runtime.h>

// Problem constants (B=64, T=512, I=256, H=512)
#define BATCH 64
#define TSTEPS 512
#define IDIM 256
#define HDIM 512
#define MROWS (BATCH * TSTEPS)   // 32768

typedef __attribute__((address_space(1))) const void gvoid;
typedef __attribute__((address_space(3))) void lvoid;

__device__ __forceinline__ void gl2lds16(const void* g, void* l) {
    // async global->LDS, 16B per lane; LDS dest = wave-uniform base + lane*16
    __builtin_amdgcn_global_load_lds((gvoid*)g, (lvoid*)l, 16, 0, 0);
}

// ---------------------------------------------------------------------------
// K0: extract center taps: W1T[i][h] = conv1_w[h][i][1] ([k][n] layout);
//                          W2T[h][j] = conv2_w[j][h][1] ([k][n] layout)
// ---------------------------------------------------------------------------
__global__ void extract_weights(const float* __restrict__ c1w,
                                const float* __restrict__ c2w,
                                float* __restrict__ W1T,
                                float* __restrict__ W2T) {
    int tid = blockIdx.x * 256 + threadIdx.x;
    if (tid < IDIM * HDIM) {
        int i = tid >> 9;          // / 512
        int h = tid & 511;
        W1T[tid] = c1w[(h * IDIM + i) * 3 + 1];
    }
    if (tid < HDIM * HDIM) {
        int h = tid >> 9;
        int j = tid & 511;
        W2T[tid] = c2w[(j * HDIM + h) * 3 + 1];
    }
}

// ---------------------------------------------------------------------------
// fp32 GEMM: C[m][n] = (sum_k A[m][k]*BT[k][n]) [+ bias[n]]
// NUMERICS CONTRACT: each output is ONE sequential fmaf chain, k ascending,
// fp32 — bitwise identical to the round-1 kernel that passed with absmax 0.0.
// (MFMA / split-K / tree reductions flip spikes — rounds 2/3 evidence.)
//
// BM=BN=128, BK=16, 256 threads (4 waves, 2x2 wave grid), 8x8 per thread.
// As staged TRANSPOSED [k][m] (scalar ds_writes, 2-way conflicts = free) so
// compute-side A reads are float4 with 8-way broadcast + 2-way alias (free).
// Bs staged via global_load_lds width-16 (BT already [k][n] contiguous).
// Inner k-step: 4x ds_read_b128 + 64x v_fmac -> ~94% FMA density.
// ---------------------------------------------------------------------------
#define BM 128
#define BN 128
#define BK 16

__global__ __launch_bounds__(256, 2) void gemm_f32(const float* __restrict__ A,
                                                   const float* __restrict__ BT,
                                                   const float* __restrict__ bias,
                                                   float* __restrict__ C,
                                                   int K, int addBias) {
    __shared__ __align__(16) float As[BK * BM];   // [k][m]  8 KB
    __shared__ __align__(16) float Bs[BK * BN];   // [k][n]  8 KB

    const int N = HDIM;
    int tid  = threadIdx.x;
    int lane = tid & 63;
    int wave = tid >> 6;
    int row0 = blockIdx.x * BM;
    int col0 = blockIdx.y * BN;
    int wm = (wave >> 1) * 64;      // wave quadrant
    int wn = (wave & 1) * 64;
    int mbase = wm + (lane >> 3) * 8;   // this thread's 8 rows (tile-local)
    int nbase = wn + (lane & 7) * 8;    // this thread's 8 cols (tile-local)

    float acc[8][8];
#pragma unroll
    for (int i = 0; i < 8; i++)
#pragma unroll
        for (int j = 0; j < 8; j++) acc[i][j] = 0.0f;

    // A staging: thread t loads 8 consecutive floats of row (t>>1),
    // k-half (t&1)*8, then scatters transposed into As[k][m].
    int ar = tid >> 1;              // 0..127
    int ak = (tid & 1) * 8;         // 0 or 8
    const float* ap = A + (size_t)(row0 + ar) * K + ak;

    // B staging: thread t copies 16B chunk: k-row (t>>5), n-chunk (t&31).
    const char* bp = (const char*)(BT + (size_t)(tid >> 5) * N + col0 + (tid & 31) * 4);
    char* bld = (char*)Bs + tid * 16;
    const size_t bRow8 = (size_t)8 * N * sizeof(float);   // +8 k-rows

    for (int k0 = 0; k0 < K; k0 += BK) {
        gl2lds16(bp, bld);
        gl2lds16(bp + bRow8, bld + 4096);
        float4 a0 = *(const float4*)(ap);
        float4 a1 = *(const float4*)(ap + 4);
        ap += BK;
        bp += (size_t)BK * N * sizeof(float);
        As[(ak + 0) * BM + ar] = a0.x;
        As[(ak + 1) * BM + ar] = a0.y;
        As[(ak + 2) * BM + ar] = a0.z;
        As[(ak + 3) * BM + ar] = a0.w;
        As[(ak + 4) * BM + ar] = a1.x;
        As[(ak + 5) * BM + ar] = a1.y;
        As[(ak + 6) * BM + ar] = a1.z;
        As[(ak + 7) * BM + ar] = a1.w;
        __syncthreads();

#pragma unroll
        for (int k = 0; k < BK; k++) {
            float4 av0 = *(const float4*)&As[k * BM + mbase];
            float4 av1 = *(const float4*)&As[k * BM + mbase + 4];
            float4 bv0 = *(const float4*)&Bs[k * BN + nbase];
            float4 bv1 = *(const float4*)&Bs[k * BN + nbase + 4];
            float a8[8] = {av0.x, av0.y, av0.z, av0.w, av1.x, av1.y, av1.z, av1.w};
            float b8[8] = {bv0.x, bv0.y, bv0.z, bv0.w, bv1.x, bv1.y, bv1.z, bv1.w};
#pragma unroll
            for (int i = 0; i < 8; i++)
#pragma unroll
                for (int j = 0; j < 8; j++)
                    acc[i][j] = fmaf(a8[i], b8[j], acc[i][j]);
        }
        __syncthreads();
    }

    // Epilogue: v = acc (+ bias), float4 stores
    float b8[8];
#pragma unroll
    for (int j = 0; j < 8; j++)
        b8[j] = addBias ? bias[col0 + nbase + j] : 0.0f;
#pragma unroll
    for (int i = 0; i < 8; i++) {
        int row = row0 + mbase + i;
        float v[8];
#pragma unroll
        for (int j = 0; j < 8; j++) {
            v[j] = acc[i][j];
            if (addBias) v[j] += b8[j];
        }
        float4* cp = (float4*)&C[(size_t)row * N + col0 + nbase];
        cp[0] = (float4){v[0], v[1], v[2], v[3]};
        cp[1] = (float4){v[4], v[5], v[6], v[7]};
    }
}

// ---------------------------------------------------------------------------
// K2: per-(b,h) LIF scan. 64-thread blocks (512 blocks -> 2/CU) + 16-deep ILP.
// Arithmetic identical to round 1 (sequential per element).
// ---------------------------------------------------------------------------
__global__ void lif_scan1(const float* __restrict__ z1,
                          float* __restrict__ s1,
                          const float* __restrict__ th_p) {
    int gtid = blockIdx.x * blockDim.x + threadIdx.x;   // 0..32767
    int b = gtid >> 9;
    int h = gtid & 511;
    float th = *th_p;
    const float* zp = z1 + (size_t)b * TSTEPS * HDIM + h;
    float* sp = s1 + (size_t)b * TSTEPS * HDIM + h;
    float m = 0.0f;
    for (int t0 = 0; t0 < TSTEPS; t0 += 16) {
        float zz[16];
#pragma unroll
        for (int i = 0; i < 16; i++) zz[i] = zp[(size_t)(t0 + i) * HDIM];
        float ss[16];
#pragma unroll
        for (int i = 0; i < 16; i++) {
            m += zz[i];
            float thr = m / th - 1.0f;
            ss[i] = (thr >= 0.0f) ? 1.0f : 0.0f;
            if (thr > 0.0f) m -= th;   // exact: m - th*1.0
        }
#pragma unroll
        for (int i = 0; i < 16; i++) sp[(size_t)(t0 + i) * HDIM] = ss[i];
    }
}

// ---------------------------------------------------------------------------
// K4: per-(b,j) scan: m2 = (m2 + raw[t]) + bias, spike/reset -> out
// ---------------------------------------------------------------------------
__global__ void lif_scan2(const float* __restrict__ raw,
                          const float* __restrict__ b2,
                          const float* __restrict__ th_p,
                          float* __restrict__ out) {
    int gtid = blockIdx.x * blockDim.x + threadIdx.x;   // 0..32767
    int b = gtid >> 9;
    int j = gtid & 511;
    float th = *th_p;
    float bias = b2[j];
    const float* rp = raw + (size_t)b * TSTEPS * HDIM + j;
    float* op = out + (size_t)b * TSTEPS * HDIM + j;
    float m = 0.0f;
    for (int t0 = 0; t0 < TSTEPS; t0 += 16) {
        float rr[16];
#pragma unroll
        for (int i = 0; i < 16; i++) rr[i] = rp[(size_t)(t0 + i) * HDIM];
        float ss[16];
#pragma unroll
        for (int i = 0; i < 16; i++) {
            m = (m + rr[i]) + bias;
            float thr = m / th - 1.0f;
            ss[i] = (thr >= 0.0f) ? 1.0f : 0.0f;
            if (thr > 0.0f) m -= th;
        }
#pragma unroll
        for (int i = 0; i < 16; i++) op[(size_t)(t0 + i) * HDIM] = ss[i];
    }
}

// ---------------------------------------------------------------------------
extern "C" void kernel_launch(void* const* d_in, const int* in_sizes, int n_in,
                              void* d_out, int out_size, void* d_ws, size_t ws_size,
                              hipStream_t stream) {
    const float* x    = (const float*)d_in[0];   // (64, 512, 256)
    const float* c1w  = (const float*)d_in[1];   // (512, 256, 3)
    const float* c1b  = (const float*)d_in[2];   // (512,)
    const float* c2w  = (const float*)d_in[3];   // (512, 512, 3)
    const float* c2b  = (const float*)d_in[4];   // (512,)
    const float* th1  = (const float*)d_in[5];   // scalar
    const float* th2  = (const float*)d_in[6];   // scalar
    float* out = (float*)d_out;                  // (64, 512, 512)

    // Workspace layout (floats):
    //   W1T : 131072   (512 KB)   [k=i][n=h]
    //   W2T : 262144   (1 MB)     [k=h][n=j]
    //   bufA: 16777216 (64 MB)    z1, later m2raw
    //   bufS: 16777216 (64 MB)    s1
    float* W1T  = (float*)d_ws;
    float* W2T  = W1T + IDIM * HDIM;
    float* bufA = W2T + HDIM * HDIM;
    float* bufS = bufA + (size_t)MROWS * HDIM;

    // K0: weight extraction
    extract_weights<<<(HDIM * HDIM + 255) / 256, 256, 0, stream>>>(c1w, c2w, W1T, W2T);

    // K1: z1 = x @ W1T + b1   (M=32768, K=256, N=512) -> bufA
    {
        dim3 grid(MROWS / BM, HDIM / BN);
        gemm_f32<<<grid, 256, 0, stream>>>(x, W1T, c1b, bufA, IDIM, 1);
    }

    // K2: s1 scan -> bufS
    lif_scan1<<<MROWS / 64, 64, 0, stream>>>(bufA, bufS, th1);

    // K3: m2raw = s1 @ W2T   (M=32768, K=512, N=512) -> bufA
    {
        dim3 grid(MROWS / BM, HDIM / BN);
        gemm_f32<<<grid, 256, 0, stream>>>(bufS, W2T, (const float*)nullptr, bufA, HDIM, 0);
    }

    // K4: s2 scan -> out
    lif_scan2<<<MROWS / 64, 64, 0, stream>>>(bufA, c2b, th2, out);
}